// Round 6
// baseline (665.474 us; speedup 1.0000x reference)
//
#include <hip/hip_runtime.h>
#include <hip/hip_bf16.h>

#define T_TOK 2048
#define H_DIM 2048
#define F_DIM 1408
#define N_EXP 8
#define BM 128
#define BN 64
#define BK 64

// work-item grid: x = item slot (40 covers worst case sum ceil(cnt/128) <= 39)
#define NITEM 40
#define G1_NY (F_DIM / BN)   // 22
#define G2_NY (H_DIM / BN)   // 32
#define G1_CHUNK ((NITEM * G1_NY) / 8)  // 110
#define G2_CHUNK ((NITEM * G2_NY) / 8)  // 160

typedef float f32x4 __attribute__((ext_vector_type(4)));
typedef short s16x8 __attribute__((ext_vector_type(8)));

// swizzled LDS byte offset: rows are 128B (64 bf16); XOR bits[4:6] with row&7
#define LOFF(row, kbyte) (((row) << 7) + ((kbyte) ^ (((row) & 7) << 4)))

__device__ __forceinline__ int bf2i(__hip_bfloat162 h) {
  int r; __builtin_memcpy(&r, &h, 4); return r;
}

__device__ __forceinline__ int4 pack8(float4 a, float4 b) {
  int4 r;
  r.x = bf2i(__float22bfloat162_rn(float2{a.x, a.y}));
  r.y = bf2i(__float22bfloat162_rn(float2{a.z, a.w}));
  r.z = bf2i(__float22bfloat162_rn(float2{b.x, b.y}));
  r.w = bf2i(__float22bfloat162_rn(float2{b.z, b.w}));
  return r;
}

__device__ __forceinline__ unsigned short f2bf(float f) {
  __hip_bfloat16 h = __float2bfloat16(f);
  unsigned short r; __builtin_memcpy(&r, &h, 2); return r;
}

__device__ __forceinline__ f32x4 mfma16(s16x8 a, s16x8 b, f32x4 c) {
  return __builtin_amdgcn_mfma_f32_16x16x32_bf16(a, b, c, 0, 0, 0);
}

// ---------------- router (+ fused x->bf16 cast) ----------------
__global__ void router_kernel(const float* __restrict__ x, const float* __restrict__ gw,
                              float* __restrict__ logits, int* __restrict__ tk_idx,
                              float* __restrict__ tk_w, unsigned short* __restrict__ xb) {
  __shared__ float xs[H_DIM];
  __shared__ float lg[N_EXP];
  const int t = blockIdx.x;
  const int tid = threadIdx.x;
  const float4 xv = ((const float4*)(x + (size_t)t * H_DIM))[tid];
  ((float4*)xs)[tid] = xv;
  int2 cw;
  cw.x = bf2i(__float22bfloat162_rn(float2{xv.x, xv.y}));
  cw.y = bf2i(__float22bfloat162_rn(float2{xv.z, xv.w}));
  ((int2*)(xb + (size_t)t * H_DIM))[tid] = cw;
  __syncthreads();
  const int w = tid >> 6, l = tid & 63;
  const float* g = gw + w * H_DIM;
  float s = 0.f;
  for (int j = l; j < H_DIM; j += 64) s += xs[j] * g[j];
#pragma unroll
  for (int o = 32; o; o >>= 1) s += __shfl_down(s, o);
  if (l == 0) lg[w] = s;
  __syncthreads();
  if (tid == 0) {
    float mx = lg[0];
#pragma unroll
    for (int i = 1; i < N_EXP; i++) mx = fmaxf(mx, lg[i]);
    float p[N_EXP];
#pragma unroll
    for (int i = 0; i < N_EXP; i++) p[i] = __expf(lg[i] - mx);
    int i0 = 0;
#pragma unroll
    for (int i = 1; i < N_EXP; i++) if (p[i] > p[i0]) i0 = i;
    int i1 = (i0 == 0) ? 1 : 0;
#pragma unroll
    for (int i = 0; i < N_EXP; i++) if (i != i0 && p[i] > p[i1]) i1 = i;
    const float ww = p[i0] + p[i1];
    tk_idx[t * 2] = i0; tk_idx[t * 2 + 1] = i1;
    tk_w[t * 2] = p[i0] / ww; tk_w[t * 2 + 1] = p[i1] / ww;
#pragma unroll
    for (int i = 0; i < N_EXP; i++) logits[t * N_EXP + i] = lg[i];
  }
}

// ---------------- deterministic per-expert list build (1 block/expert) ----------------
__global__ void build_lists(const int* __restrict__ tk_idx, const float* __restrict__ tk_w,
                            int* __restrict__ counts, int* __restrict__ entries,
                            float* __restrict__ wlist) {
  const int e = blockIdx.x;
  const int l = threadIdx.x;
  int base = 0;
  for (int t0 = 0; t0 < T_TOK; t0 += 64) {
    const int t = t0 + l;
    int sel = -1; float w = 0.f;
    const int i0 = tk_idx[t * 2], i1 = tk_idx[t * 2 + 1];
    if (i0 == e) { sel = t * 2; w = tk_w[t * 2]; }
    else if (i1 == e) { sel = t * 2 + 1; w = tk_w[t * 2 + 1]; }
    const unsigned long long mask = __ballot(sel >= 0);
    const int pos = base + __popcll(mask & ((1ull << l) - 1ull));
    if (sel >= 0) { entries[e * T_TOK + pos] = sel; wlist[e * T_TOK + pos] = w; }
    base += __popcll(mask);
  }
  if (l == 0) counts[e] = base;
}

// ---------------- dense work-item table: items[0]=n, items[1+i]=(e<<16)|mtile ----------------
__global__ void build_items(const int* __restrict__ counts, int* __restrict__ items) {
  if (threadIdx.x == 0) {
    int n = 0;
#pragma unroll
    for (int e = 0; e < N_EXP; e++) {
      const int c = counts[e];
      for (int m0 = 0; m0 < c; m0 += BM) items[1 + n++] = (e << 16) | (m0 / BM);
    }
    items[0] = n;
  }
}

// ---------------- GEMM1: h = silu(x@w1^T) * (x@w3^T), bf16 out ----------------
// 4 waves (2m x 2n), wave tile 64x32. A-frags gathered DIRECTLY from global
// (xb is L2/L3-resident; 16 fully-used 64B lines per gather). Only B (weights,
// fp32->bf16 pack) goes through LDS: double-buffered, 1 barrier/step.
// LDS traffic per block-step: 48KB (was 144KB) for the same 128 MFMAs.
#define G1_STEP(SW1, SW3, SR1, SR3, A0C, A0N, KB_, KA_, KN_)                  \
  {                                                                           \
    asm volatile("s_waitcnt lgkmcnt(0)" ::: "memory");                        \
    __builtin_amdgcn_s_barrier();                                             \
    *(int4*)((SW1) + offB0) = pack8(rb1[0][0], rb1[0][1]);                    \
    *(int4*)((SW1) + offB1) = pack8(rb1[1][0], rb1[1][1]);                    \
    *(int4*)((SW3) + offB0) = pack8(rb3[0][0], rb3[0][1]);                    \
    *(int4*)((SW3) + offB1) = pack8(rb3[1][0], rb3[1][1]);                    \
    {                                                                         \
      const int kbl = (KB_);                                                  \
      rb1[0][0] = *(const float4*)(pb1 + kbl);                                \
      rb1[0][1] = *(const float4*)(pb1 + kbl + 4);                            \
      rb1[1][0] = *(const float4*)(pb1 + rstep + kbl);                        \
      rb1[1][1] = *(const float4*)(pb1 + rstep + kbl + 4);                    \
      rb3[0][0] = *(const float4*)(pb3 + kbl);                                \
      rb3[0][1] = *(const float4*)(pb3 + kbl + 4);                            \
      rb3[1][0] = *(const float4*)(pb3 + rstep + kbl);                        \
      rb3[1][1] = *(const float4*)(pb3 + rstep + kbl + 4);                    \
    }                                                                         \
    s16x8 a1[4];                                                              \
    _Pragma("unroll")                                                         \
    for (int m = 0; m < 4; m++) {                                             \
      A0N[m] = *(const s16x8*)(xb + aoff[m] + (KN_) + lk);                    \
      a1[m] = *(const s16x8*)(xb + aoff[m] + (KA_) + 32 + lk);                \
    }                                                                         \
    {                                                                         \
      const s16x8 b10 = *(const s16x8*)((SR1) + LOFF(rowB0, kb));             \
      const s16x8 b11 = *(const s16x8*)((SR1) + LOFF(rowB1, kb));             \
      const s16x8 b30 = *(const s16x8*)((SR3) + LOFF(rowB0, kb));             \
      const s16x8 b31 = *(const s16x8*)((SR3) + LOFF(rowB1, kb));             \
      _Pragma("unroll")                                                       \
      for (int m = 0; m < 4; m++) {                                           \
        aG[m][0] = mfma16(A0C[m], b10, aG[m][0]);                             \
        aG[m][1] = mfma16(A0C[m], b11, aG[m][1]);                             \
        aU[m][0] = mfma16(A0C[m], b30, aU[m][0]);                             \
        aU[m][1] = mfma16(A0C[m], b31, aU[m][1]);                             \
      }                                                                       \
      const s16x8 c10 = *(const s16x8*)((SR1) + LOFF(rowB0, 64 + kb));        \
      const s16x8 c11 = *(const s16x8*)((SR1) + LOFF(rowB1, 64 + kb));        \
      const s16x8 c30 = *(const s16x8*)((SR3) + LOFF(rowB0, 64 + kb));        \
      const s16x8 c31 = *(const s16x8*)((SR3) + LOFF(rowB1, 64 + kb));        \
      _Pragma("unroll")                                                       \
      for (int m = 0; m < 4; m++) {                                           \
        aG[m][0] = mfma16(a1[m], c10, aG[m][0]);                              \
        aG[m][1] = mfma16(a1[m], c11, aG[m][1]);                              \
        aU[m][0] = mfma16(a1[m], c30, aU[m][0]);                              \
        aU[m][1] = mfma16(a1[m], c31, aU[m][1]);                              \
      }                                                                       \
    }                                                                         \
  }

__global__ __launch_bounds__(256)
void moe_gemm1(const float* __restrict__ w1, const float* __restrict__ w3,
               const unsigned short* __restrict__ xb,
               const int* __restrict__ counts, const int* __restrict__ entries,
               const int* __restrict__ items,
               unsigned short* __restrict__ hb) {
  // XCD-chunked bijective swizzle: 880 = 8 * 110
  const int lin = blockIdx.x;
  const int virt = (lin & 7) * G1_CHUNK + (lin >> 3);
  const int ix = virt % NITEM;
  const int iy = virt / NITEM;
  if (ix >= items[0]) return;
  const int it = items[1 + ix];
  const int e = it >> 16;
  const int m0 = (it & 0xffff) * BM;
  const int rem = counts[e] - m0;
  const int n0 = iy * BN;

  __shared__ unsigned short sB1[2][BN * BK];
  __shared__ unsigned short sB3[2][BN * BK];
  char* s1a = (char*)sB1[0]; char* s1b = (char*)sB1[1];
  char* s3a = (char*)sB3[0]; char* s3b = (char*)sB3[1];

  const int tid = threadIdx.x;
  const int lane = tid & 63;
  const int wave = tid >> 6;
  const int wm = wave >> 1, wn = wave & 1;

  const int* elist = entries + e * T_TOK + m0;

  // B staging: 256 thr, rows r0 and r0+32, 16B bf16 (8 fp32) each
  const int r0 = tid >> 3;
  const int gc = tid & 7;
  const float* pb1 = w1 + ((size_t)e * F_DIM + n0 + r0) * H_DIM + gc * 8;
  const float* pb3 = w3 + ((size_t)e * F_DIM + n0 + r0) * H_DIM + gc * 8;
  const size_t rstep = (size_t)32 * H_DIM;
  const int offB0 = LOFF(r0, gc * 16);
  const int offB1 = LOFF(r0 + 32, gc * 16);

  // A direct-gather setup: frag row = lane&15, k-oct = lane>>4
  const int lr = lane & 15;
  const int lk = (lane >> 4) * 8;
  int aoff[4];
#pragma unroll
  for (int m = 0; m < 4; m++) {
    int q = wm * 64 + m * 16 + lr;
    q = q < rem ? q : 0;
    aoff[m] = (elist[q] >> 1) * H_DIM;
  }

  const int rowB0 = wn * 32 + lr;
  const int rowB1 = rowB0 + 16;
  const int kb = (lane >> 4) * 16;

  const f32x4 zero = {0.f, 0.f, 0.f, 0.f};
  f32x4 aG[4][2], aU[4][2];
#pragma unroll
  for (int m = 0; m < 4; m++) { aG[m][0] = zero; aG[m][1] = zero; aU[m][0] = zero; aU[m][1] = zero; }

  // prologue: B tile0 -> regs -> buf0; B tile1 -> regs; A kk0 of tile0 -> Pa0
  float4 rb1[2][2], rb3[2][2];
  rb1[0][0] = *(const float4*)(pb1);         rb1[0][1] = *(const float4*)(pb1 + 4);
  rb1[1][0] = *(const float4*)(pb1 + rstep); rb1[1][1] = *(const float4*)(pb1 + rstep + 4);
  rb3[0][0] = *(const float4*)(pb3);         rb3[0][1] = *(const float4*)(pb3 + 4);
  rb3[1][0] = *(const float4*)(pb3 + rstep); rb3[1][1] = *(const float4*)(pb3 + rstep + 4);
  *(int4*)(s1a + offB0) = pack8(rb1[0][0], rb1[0][1]);
  *(int4*)(s1a + offB1) = pack8(rb1[1][0], rb1[1][1]);
  *(int4*)(s3a + offB0) = pack8(rb3[0][0], rb3[0][1]);
  *(int4*)(s3a + offB1) = pack8(rb3[1][0], rb3[1][1]);
  rb1[0][0] = *(const float4*)(pb1 + BK);         rb1[0][1] = *(const float4*)(pb1 + BK + 4);
  rb1[1][0] = *(const float4*)(pb1 + rstep + BK); rb1[1][1] = *(const float4*)(pb1 + rstep + BK + 4);
  rb3[0][0] = *(const float4*)(pb3 + BK);         rb3[0][1] = *(const float4*)(pb3 + BK + 4);
  rb3[1][0] = *(const float4*)(pb3 + rstep + BK); rb3[1][1] = *(const float4*)(pb3 + rstep + BK + 4);
  s16x8 Pa0[4], Qa0[4];
#pragma unroll
  for (int m = 0; m < 4; m++) Pa0[m] = *(const s16x8*)(xb + aoff[m] + lk);

  const int NT = H_DIM / BK;  // 32 (even)
  for (int t = 0; t < NT; t += 2) {
    const int kb2 = (t + 2 < NT) ? (t + 2) * BK : 0;
    const int kb3 = (t + 3 < NT) ? (t + 3) * BK : 0;
    G1_STEP(s1b, s3b, s1a, s3a, Pa0, Qa0, kb2, t * BK, (t + 1) * BK);
    G1_STEP(s1a, s3a, s1b, s3b, Qa0, Pa0, kb3, (t + 1) * BK, kb2);
  }

  // epilogue: h = silu(g)*u -> bf16 scatter by entry row
#pragma unroll
  for (int m = 0; m < 4; m++) {
#pragma unroll
    for (int r = 0; r < 4; r++) {
      const int mr = wm * 64 + m * 16 + (lane >> 4) * 4 + r;
      if (mr < rem) {
        const int entry = elist[mr];
        unsigned short* hp = hb + (size_t)entry * F_DIM + n0 + wn * 32 + lr;
#pragma unroll
        for (int n = 0; n < 2; n++) {
          const float g = aG[m][n][r];
          const float u = aU[m][n][r];
          hp[n * 16] = f2bf(g / (1.f + __expf(-g)) * u);
        }
      }
    }
  }
}

// ---------------- GEMM2: y = h@w2^T, weighted atomic combine ----------------
#define G2_STEP(SW, SR, A0C, A0N, KB_, KA_, KN_)                              \
  {                                                                           \
    asm volatile("s_waitcnt lgkmcnt(0)" ::: "memory");                        \
    __builtin_amdgcn_s_barrier();                                             \
    *(int4*)((SW) + offB0) = pack8(rb[0][0], rb[0][1]);                       \
    *(int4*)((SW) + offB1) = pack8(rb[1][0], rb[1][1]);                       \
    {                                                                         \
      const int kbl = (KB_);                                                  \
      rb[0][0] = *(const float4*)(pb + kbl);                                  \
      rb[0][1] = *(const float4*)(pb + kbl + 4);                              \
      rb[1][0] = *(const float4*)(pb + rstep + kbl);                          \
      rb[1][1] = *(const float4*)(pb + rstep + kbl + 4);                      \
    }                                                                         \
    s16x8 a1[4];                                                              \
    _Pragma("unroll")                                                         \
    for (int m = 0; m < 4; m++) {                                             \
      A0N[m] = *(const s16x8*)(hb + aoff[m] + (KN_) + lk);                    \
      a1[m] = *(const s16x8*)(hb + aoff[m] + (KA_) + 32 + lk);                \
    }                                                                         \
    {                                                                         \
      const s16x8 b0 = *(const s16x8*)((SR) + LOFF(rowB0, kb));               \
      const s16x8 b1 = *(const s16x8*)((SR) + LOFF(rowB1, kb));               \
      _Pragma("unroll")                                                       \
      for (int m = 0; m < 4; m++) {                                           \
        ac[m][0] = mfma16(A0C[m], b0, ac[m][0]);                              \
        ac[m][1] = mfma16(A0C[m], b1, ac[m][1]);                              \
      }                                                                       \
      const s16x8 c0 = *(const s16x8*)((SR) + LOFF(rowB0, 64 + kb));          \
      const s16x8 c1 = *(const s16x8*)((SR) + LOFF(rowB1, 64 + kb));          \
      _Pragma("unroll")                                                       \
      for (int m = 0; m < 4; m++) {                                           \
        ac[m][0] = mfma16(a1[m], c0, ac[m][0]);                               \
        ac[m][1] = mfma16(a1[m], c1, ac[m][1]);                               \
      }                                                                       \
    }                                                                         \
  }

__global__ __launch_bounds__(256)
void moe_gemm2(const float* __restrict__ w2,
               const unsigned short* __restrict__ hb,
               const int* __restrict__ counts, const int* __restrict__ entries,
               const float* __restrict__ wlist, const int* __restrict__ items,
               float* __restrict__ out) {
  // XCD-chunked bijective swizzle: 1280 = 8 * 160
  const int lin = blockIdx.x;
  const int virt = (lin & 7) * G2_CHUNK + (lin >> 3);
  const int ix = virt % NITEM;
  const int iy = virt / NITEM;
  if (ix >= items[0]) return;
  const int it = items[1 + ix];
  const int e = it >> 16;
  const int m0 = (it & 0xffff) * BM;
  const int rem = counts[e] - m0;
  const int n0 = iy * BN;

  __shared__ unsigned short sB[2][BN * BK];
  char* sa = (char*)sB[0]; char* sb = (char*)sB[1];

  const int tid = threadIdx.x;
  const int lane = tid & 63;
  const int wave = tid >> 6;
  const int wm = wave >> 1, wn = wave & 1;

  const int* elist = entries + e * T_TOK + m0;
  const float* wl = wlist + e * T_TOK + m0;

  const int r0 = tid >> 3;
  const int gc = tid & 7;
  const float* pb = w2 + ((size_t)e * H_DIM + n0 + r0) * F_DIM + gc * 8;
  const size_t rstep = (size_t)32 * F_DIM;
  const int offB0 = LOFF(r0, gc * 16);
  const int offB1 = LOFF(r0 + 32, gc * 16);

  const int lr = lane & 15;
  const int lk = (lane >> 4) * 8;
  int aoff[4];
#pragma unroll
  for (int m = 0; m < 4; m++) {
    int q = wm * 64 + m * 16 + lr;
    q = q < rem ? q : 0;
    aoff[m] = elist[q] * F_DIM;
  }

  const int rowB0 = wn * 32 + lr;
  const int rowB1 = rowB0 + 16;
  const int kb = (lane >> 4) * 16;

  const f32x4 zero = {0.f, 0.f, 0.f, 0.f};
  f32x4 ac[4][2];
#pragma unroll
  for (int m = 0; m < 4; m++) { ac[m][0] = zero; ac[m][1] = zero; }

  float4 rb[2][2];
  rb[0][0] = *(const float4*)(pb);         rb[0][1] = *(const float4*)(pb + 4);
  rb[1][0] = *(const float4*)(pb + rstep); rb[1][1] = *(const float4*)(pb + rstep + 4);
  *(int4*)(sa + offB0) = pack8(rb[0][0], rb[0][1]);
  *(int4*)(sa + offB1) = pack8(rb[1][0], rb[1][1]);
  rb[0][0] = *(const float4*)(pb + BK);         rb[0][1] = *(const float4*)(pb + BK + 4);
  rb[1][0] = *(const float4*)(pb + rstep + BK); rb[1][1] = *(const float4*)(pb + rstep + BK + 4);
  s16x8 Pa0[4], Qa0[4];
#pragma unroll
  for (int m = 0; m < 4; m++) Pa0[m] = *(const s16x8*)(hb + aoff[m] + lk);

  const int NT = F_DIM / BK;  // 22 (even)
  for (int t = 0; t < NT; t += 2) {
    const int kb2 = (t + 2 < NT) ? (t + 2) * BK : 0;
    const int kb3 = (t + 3 < NT) ? (t + 3) * BK : 0;
    G2_STEP(sb, sa, Pa0, Qa0, kb2, t * BK, (t + 1) * BK);
    G2_STEP(sa, sb, Qa0, Pa0, kb3, (t + 1) * BK, kb2);
  }

#pragma unroll
  for (int m = 0; m < 4; m++) {
#pragma unroll
    for (int r = 0; r < 4; r++) {
      const int mr = wm * 64 + m * 16 + (lane >> 4) * 4 + r;
      if (mr < rem) {
        const int entry = elist[mr];
        const int tok = entry >> 1;
        const float wgt = wl[mr];
        float* op = out + (size_t)tok * H_DIM + n0 + wn * 32 + lr;
#pragma unroll
        for (int n = 0; n < 2; n++) atomicAdd(op + n * 16, wgt * ac[m][n][r]);
      }
    }
  }
}

extern "C" void kernel_launch(void* const* d_in, const int* in_sizes, int n_in,
                              void* d_out, int out_size, void* d_ws, size_t ws_size,
                              hipStream_t stream) {
  const float* x  = (const float*)d_in[0];
  const float* gw = (const float*)d_in[1];
  const float* w1 = (const float*)d_in[2];
  const float* w3 = (const float*)d_in[3];
  const float* w2 = (const float*)d_in[4];
  float* out = (float*)d_out;
  float* logits = out + (size_t)T_TOK * H_DIM;

  char* ws = (char*)d_ws;
  size_t off = 0;
  unsigned short* xb = (unsigned short*)(ws + off); off += (size_t)T_TOK * H_DIM * 2;      // 8 MB
  unsigned short* hb = (unsigned short*)(ws + off); off += (size_t)T_TOK * 2 * F_DIM * 2;  // 11.5 MB
  int*   tk_idx = (int*)(ws + off);   off += (size_t)T_TOK * 2 * 4;
  float* tk_w   = (float*)(ws + off); off += (size_t)T_TOK * 2 * 4;
  int*   counts = (int*)(ws + off);   off += 256;
  int*   entries = (int*)(ws + off);  off += (size_t)N_EXP * T_TOK * 4;
  float* wlist  = (float*)(ws + off); off += (size_t)N_EXP * T_TOK * 4;
  int*   items  = (int*)(ws + off);   off += 256;

  (void)hipMemsetAsync(d_out, 0, (size_t)out_size * sizeof(float), stream);
  router_kernel<<<dim3(T_TOK), 512, 0, stream>>>(x, gw, logits, tk_idx, tk_w, xb);
  build_lists<<<dim3(N_EXP), 64, 0, stream>>>(tk_idx, tk_w, counts, entries, wlist);
  build_items<<<dim3(1), 64, 0, stream>>>(counts, items);
  moe_gemm1<<<dim3(NITEM * G1_NY), 256, 0, stream>>>(w1, w3, xb, counts, entries, items, hb);
  moe_gemm2<<<dim3(NITEM * G2_NY), 256, 0, stream>>>(w2, hb, counts, entries, wlist, items, out);
}

// Round 7
// 233.555 us; speedup vs baseline: 2.8493x; 2.8493x over previous
//
#include <hip/hip_runtime.h>
#include <hip/hip_bf16.h>

#define T_TOK 2048
#define H_DIM 2048
#define F_DIM 1408
#define N_EXP 8
#define BM 128
#define BN 64
#define BK 64

// work-item grid: x = item slot (40 covers worst case sum ceil(cnt/128) <= 39)
#define NITEM 40
#define G1_NY (F_DIM / BN)   // 22
#define G2_NY (H_DIM / BN)   // 32
#define G1_CHUNK ((NITEM * G1_NY) / 8)  // 110
#define G2_CHUNK ((NITEM * G2_NY) / 8)  // 160

typedef float f32x4 __attribute__((ext_vector_type(4)));
typedef short s16x8 __attribute__((ext_vector_type(8)));
typedef unsigned int u32;

// swizzled LDS byte offset: rows are 128B (64 bf16); XOR bits[4:6] with row&7
#define LOFF(row, kbyte) (((row) << 7) + ((kbyte) ^ (((row) & 7) << 4)))

__device__ __forceinline__ int bf2i(__hip_bfloat162 h) {
  int r; __builtin_memcpy(&r, &h, 4); return r;
}

__device__ __forceinline__ int4 pack8(float4 a, float4 b) {
  int4 r;
  r.x = bf2i(__float22bfloat162_rn(float2{a.x, a.y}));
  r.y = bf2i(__float22bfloat162_rn(float2{a.z, a.w}));
  r.z = bf2i(__float22bfloat162_rn(float2{b.x, b.y}));
  r.w = bf2i(__float22bfloat162_rn(float2{b.z, b.w}));
  return r;
}

__device__ __forceinline__ unsigned short f2bf(float f) {
  __hip_bfloat16 h = __float2bfloat16(f);
  unsigned short r; __builtin_memcpy(&r, &h, 2); return r;
}

__device__ __forceinline__ f32x4 mfma16(s16x8 a, s16x8 b, f32x4 c) {
  return __builtin_amdgcn_mfma_f32_16x16x32_bf16(a, b, c, 0, 0, 0);
}

// async global->LDS 16B per lane; LDS dest = wave-uniform base + lane*16
__device__ __forceinline__ void dma16(const unsigned short* g, unsigned short* l) {
  __builtin_amdgcn_global_load_lds((const __attribute__((address_space(1))) u32*)g,
                                   (__attribute__((address_space(3))) u32*)l, 16, 0, 0);
}

// ---------------- router (+ fused x->bf16 cast) ----------------
__global__ void router_kernel(const float* __restrict__ x, const float* __restrict__ gw,
                              float* __restrict__ logits, int* __restrict__ tk_idx,
                              float* __restrict__ tk_w, unsigned short* __restrict__ xb) {
  __shared__ float xs[H_DIM];
  __shared__ float lg[N_EXP];
  const int t = blockIdx.x;
  const int tid = threadIdx.x;
  const float4 xv = ((const float4*)(x + (size_t)t * H_DIM))[tid];
  ((float4*)xs)[tid] = xv;
  int2 cw;
  cw.x = bf2i(__float22bfloat162_rn(float2{xv.x, xv.y}));
  cw.y = bf2i(__float22bfloat162_rn(float2{xv.z, xv.w}));
  ((int2*)(xb + (size_t)t * H_DIM))[tid] = cw;
  __syncthreads();
  const int w = tid >> 6, l = tid & 63;
  const float* g = gw + w * H_DIM;
  float s = 0.f;
  for (int j = l; j < H_DIM; j += 64) s += xs[j] * g[j];
#pragma unroll
  for (int o = 32; o; o >>= 1) s += __shfl_down(s, o);
  if (l == 0) lg[w] = s;
  __syncthreads();
  if (tid == 0) {
    float mx = lg[0];
#pragma unroll
    for (int i = 1; i < N_EXP; i++) mx = fmaxf(mx, lg[i]);
    float p[N_EXP];
#pragma unroll
    for (int i = 0; i < N_EXP; i++) p[i] = __expf(lg[i] - mx);
    int i0 = 0;
#pragma unroll
    for (int i = 1; i < N_EXP; i++) if (p[i] > p[i0]) i0 = i;
    int i1 = (i0 == 0) ? 1 : 0;
#pragma unroll
    for (int i = 0; i < N_EXP; i++) if (i != i0 && p[i] > p[i1]) i1 = i;
    const float ww = p[i0] + p[i1];
    tk_idx[t * 2] = i0; tk_idx[t * 2 + 1] = i1;
    tk_w[t * 2] = p[i0] / ww; tk_w[t * 2 + 1] = p[i1] / ww;
#pragma unroll
    for (int i = 0; i < N_EXP; i++) logits[t * N_EXP + i] = lg[i];
  }
}

// ---------------- deterministic per-expert list build (1 block/expert) ----------------
__global__ void build_lists(const int* __restrict__ tk_idx, const float* __restrict__ tk_w,
                            int* __restrict__ counts, int* __restrict__ entries,
                            float* __restrict__ wlist) {
  const int e = blockIdx.x;
  const int l = threadIdx.x;
  int base = 0;
  for (int t0 = 0; t0 < T_TOK; t0 += 64) {
    const int t = t0 + l;
    int sel = -1; float w = 0.f;
    const int i0 = tk_idx[t * 2], i1 = tk_idx[t * 2 + 1];
    if (i0 == e) { sel = t * 2; w = tk_w[t * 2]; }
    else if (i1 == e) { sel = t * 2 + 1; w = tk_w[t * 2 + 1]; }
    const unsigned long long mask = __ballot(sel >= 0);
    const int pos = base + __popcll(mask & ((1ull << l) - 1ull));
    if (sel >= 0) { entries[e * T_TOK + pos] = sel; wlist[e * T_TOK + pos] = w; }
    base += __popcll(mask);
  }
  if (l == 0) counts[e] = base;
}

// ---------------- dense work-item table: items[0]=n, items[1+i]=(e<<16)|mtile ----------------
__global__ void build_items(const int* __restrict__ counts, int* __restrict__ items) {
  if (threadIdx.x == 0) {
    int n = 0;
#pragma unroll
    for (int e = 0; e < N_EXP; e++) {
      const int c = counts[e];
      for (int m0 = 0; m0 < c; m0 += BM) items[1 + n++] = (e << 16) | (m0 / BM);
    }
    items[0] = n;
  }
}

// ---------------- GEMM1: h = silu(x@w1^T) * (x@w3^T), bf16 out ----------------
// A (bf16 token rows): async global_load_lds, double-buffered, issued 1 step
// ahead with pre-swizzled per-lane source (LDS dest linear). B (f32 weights):
// reg-staged depth-2 with cvt_pk pack, single LDS buffer, counted vmcnt entry.
#define G1_STEP(SARD, SAWR, RB1, RB3, KA1_, KB2_)                             \
  {                                                                           \
    asm volatile("s_waitcnt vmcnt(4) lgkmcnt(0)" ::: "memory");               \
    __builtin_amdgcn_s_barrier();                                             \
    *(int4*)(sB1c + offB) = pack8(RB1[0], RB1[1]);                            \
    *(int4*)(sB3c + offB) = pack8(RB3[0], RB3[1]);                            \
    {                                                                         \
      const int ka = (KA1_);                                                  \
      dma16(ga0 + ka, (SAWR) + aw);                                           \
      dma16(ga1 + ka, (SAWR) + aw + 512);                                     \
    }                                                                         \
    {                                                                         \
      const int kbl = (KB2_);                                                 \
      RB1[0] = *(const float4*)(pb1 + kbl);                                   \
      RB1[1] = *(const float4*)(pb1 + kbl + 4);                               \
      RB3[0] = *(const float4*)(pb3 + kbl);                                   \
      RB3[1] = *(const float4*)(pb3 + kbl + 4);                               \
    }                                                                         \
    asm volatile("s_waitcnt lgkmcnt(0)" ::: "memory");                        \
    __builtin_amdgcn_s_barrier();                                             \
    _Pragma("unroll")                                                         \
    for (int kk = 0; kk < 2; kk++) {                                          \
      const int kbyte = kk * 64 + kb;                                         \
      const s16x8 a0 = *(const s16x8*)((const char*)(SARD) + LOFF(rowA0, kbyte)); \
      const s16x8 a1 = *(const s16x8*)((const char*)(SARD) + LOFF(rowA1, kbyte)); \
      const s16x8 p0 = *(const s16x8*)(sB1c + LOFF(rowB0, kbyte));            \
      const s16x8 p1 = *(const s16x8*)(sB1c + LOFF(rowB1, kbyte));            \
      const s16x8 q0 = *(const s16x8*)(sB3c + LOFF(rowB0, kbyte));            \
      const s16x8 q1 = *(const s16x8*)(sB3c + LOFF(rowB1, kbyte));            \
      aG[0][0] = mfma16(a0, p0, aG[0][0]); aG[0][1] = mfma16(a0, p1, aG[0][1]); \
      aG[1][0] = mfma16(a1, p0, aG[1][0]); aG[1][1] = mfma16(a1, p1, aG[1][1]); \
      aU[0][0] = mfma16(a0, q0, aU[0][0]); aU[0][1] = mfma16(a0, q1, aU[0][1]); \
      aU[1][0] = mfma16(a1, q0, aU[1][0]); aU[1][1] = mfma16(a1, q1, aU[1][1]); \
    }                                                                         \
  }

__global__ __launch_bounds__(512)
void moe_gemm1(const float* __restrict__ w1, const float* __restrict__ w3,
               const unsigned short* __restrict__ xb,
               const int* __restrict__ counts, const int* __restrict__ entries,
               const int* __restrict__ items,
               unsigned short* __restrict__ hb) {
  // XCD-chunked bijective swizzle: 880 = 8 * 110
  const int lin = blockIdx.x;
  const int virt = (lin & 7) * G1_CHUNK + (lin >> 3);
  const int ix = virt % NITEM;
  const int iy = virt / NITEM;
  if (ix >= items[0]) return;
  const int it = items[1 + ix];
  const int e = it >> 16;
  const int m0 = (it & 0xffff) * BM;
  const int rem = counts[e] - m0;
  const int n0 = iy * BN;

  __shared__ unsigned short sA[2][BM * BK];  // 2 x 16KB
  __shared__ unsigned short sB1[BN * BK];    // 8KB
  __shared__ unsigned short sB3[BN * BK];    // 8KB
  char* sB1c = (char*)sB1; char* sB3c = (char*)sB3;

  const int tid = threadIdx.x;
  const int lane = tid & 63;
  const int wave = tid >> 6;
  const int wm = wave >> 1, wn = wave & 1;

  const int* elist = entries + e * T_TOK + m0;

  // B staging: 512 thr, row r0 in [0,64), 16B bf16 (8 f32) each
  const int r0 = tid >> 3;
  const int gc = tid & 7;
  const float* pb1 = w1 + ((size_t)e * F_DIM + n0 + r0) * H_DIM + gc * 8;
  const float* pb3 = w3 + ((size_t)e * F_DIM + n0 + r0) * H_DIM + gc * 8;
  const int offB = LOFF(r0, gc * 16);

  // A DMA: wave w covers rows 16w..16w+15 (2 insts); lane l -> row 16w+(l>>3)(+8),
  // linear dest; global col pre-swizzled so LOFF read sees swizzled layout.
  const int arow0 = wave * 16 + (lane >> 3);
  const int arow1 = arow0 + 8;
  const int gcolb = (((lane & 7) << 4) ^ (((lane >> 3) & 7) << 4));
  const int tokA0 = elist[arow0 < rem ? arow0 : 0] >> 1;
  const int tokA1 = elist[arow1 < rem ? arow1 : 0] >> 1;
  const unsigned short* ga0 = xb + (size_t)tokA0 * H_DIM + (gcolb >> 1);
  const unsigned short* ga1 = xb + (size_t)tokA1 * H_DIM + (gcolb >> 1);
  const int aw = wave * 1024;  // u16 elems: wave*2048B

  const int rowA0 = wm * 32 + (lane & 15);
  const int rowA1 = rowA0 + 16;
  const int rowB0 = wn * 32 + (lane & 15);
  const int rowB1 = rowB0 + 16;
  const int kb = (lane >> 4) * 16;

  const f32x4 zero = {0.f, 0.f, 0.f, 0.f};
  f32x4 aG[2][2], aU[2][2];
#pragma unroll
  for (int i = 0; i < 2; i++)
#pragma unroll
    for (int j = 0; j < 2; j++) { aG[i][j] = zero; aU[i][j] = zero; }

  // prologue: A-dma(0)->buf0; B(0)->P; B(1)->Q  (issue order => entry vmcnt(4))
  dma16(ga0, sA[0] + aw);
  dma16(ga1, sA[0] + aw + 512);
  float4 P1[2], P3[2], Q1[2], Q3[2];
  P1[0] = *(const float4*)(pb1);      P1[1] = *(const float4*)(pb1 + 4);
  P3[0] = *(const float4*)(pb3);      P3[1] = *(const float4*)(pb3 + 4);
  Q1[0] = *(const float4*)(pb1 + BK); Q1[1] = *(const float4*)(pb1 + BK + 4);
  Q3[0] = *(const float4*)(pb3 + BK); Q3[1] = *(const float4*)(pb3 + BK + 4);

  const int NT = H_DIM / BK;  // 32 (even)
  for (int t = 0; t < NT; t += 2) {
    const int ka1 = (t + 1 < NT) ? (t + 1) * BK : 0;
    const int ka2 = (t + 2 < NT) ? (t + 2) * BK : 0;
    const int kb2 = ka2;
    const int kb3 = (t + 3 < NT) ? (t + 3) * BK : 0;
    G1_STEP(sA[0], sA[1], P1, P3, ka1, kb2);
    G1_STEP(sA[1], sA[0], Q1, Q3, ka2, kb3);
  }

  // epilogue: h = silu(g)*u -> bf16 scatter by entry row
#pragma unroll
  for (int i = 0; i < 2; i++) {
#pragma unroll
    for (int r = 0; r < 4; r++) {
      const int m = wm * 32 + i * 16 + ((lane >> 4) << 2) + r;
      if (m < rem) {
        const int entry = elist[m];
        unsigned short* hp = hb + (size_t)entry * F_DIM + n0 + wn * 32 + (lane & 15);
#pragma unroll
        for (int j = 0; j < 2; j++) {
          const float g = aG[i][j][r];
          const float u = aU[i][j][r];
          hp[j * 16] = f2bf(g / (1.f + __expf(-g)) * u);
        }
      }
    }
  }
}

// ---------------- GEMM2: y = h@w2^T, weighted atomic combine ----------------
#define G2_STEP(SARD, SAWR, RB, KA1_, KB2_)                                   \
  {                                                                           \
    asm volatile("s_waitcnt vmcnt(2) lgkmcnt(0)" ::: "memory");               \
    __builtin_amdgcn_s_barrier();                                             \
    *(int4*)(sBc + offB) = pack8(RB[0], RB[1]);                               \
    {                                                                         \
      const int ka = (KA1_);                                                  \
      dma16(ga0 + ka, (SAWR) + aw);                                           \
      dma16(ga1 + ka, (SAWR) + aw + 512);                                     \
    }                                                                         \
    {                                                                         \
      const int kbl = (KB2_);                                                 \
      RB[0] = *(const float4*)(pb + kbl);                                     \
      RB[1] = *(const float4*)(pb + kbl + 4);                                 \
    }                                                                         \
    asm volatile("s_waitcnt lgkmcnt(0)" ::: "memory");                        \
    __builtin_amdgcn_s_barrier();                                             \
    _Pragma("unroll")                                                         \
    for (int kk = 0; kk < 2; kk++) {                                          \
      const int kbyte = kk * 64 + kb;                                         \
      const s16x8 a0 = *(const s16x8*)((const char*)(SARD) + LOFF(rowA0, kbyte)); \
      const s16x8 a1 = *(const s16x8*)((const char*)(SARD) + LOFF(rowA1, kbyte)); \
      const s16x8 f0 = *(const s16x8*)(sBc + LOFF(rowB0, kbyte));             \
      const s16x8 f1 = *(const s16x8*)(sBc + LOFF(rowB1, kbyte));             \
      ac[0][0] = mfma16(a0, f0, ac[0][0]); ac[0][1] = mfma16(a0, f1, ac[0][1]); \
      ac[1][0] = mfma16(a1, f0, ac[1][0]); ac[1][1] = mfma16(a1, f1, ac[1][1]); \
    }                                                                         \
  }

__global__ __launch_bounds__(512)
void moe_gemm2(const float* __restrict__ w2,
               const unsigned short* __restrict__ hb,
               const int* __restrict__ counts, const int* __restrict__ entries,
               const float* __restrict__ wlist, const int* __restrict__ items,
               float* __restrict__ out) {
  // XCD-chunked bijective swizzle: 1280 = 8 * 160
  const int lin = blockIdx.x;
  const int virt = (lin & 7) * G2_CHUNK + (lin >> 3);
  const int ix = virt % NITEM;
  const int iy = virt / NITEM;
  if (ix >= items[0]) return;
  const int it = items[1 + ix];
  const int e = it >> 16;
  const int m0 = (it & 0xffff) * BM;
  const int rem = counts[e] - m0;
  const int n0 = iy * BN;

  __shared__ unsigned short sA[2][BM * BK];  // 2 x 16KB
  __shared__ unsigned short sB[BN * BK];     // 8KB
  char* sBc = (char*)sB;

  const int tid = threadIdx.x;
  const int lane = tid & 63;
  const int wave = tid >> 6;
  const int wm = wave >> 1, wn = wave & 1;

  const int* elist = entries + e * T_TOK + m0;
  const float* wl = wlist + e * T_TOK + m0;

  const int r0 = tid >> 3;
  const int gc = tid & 7;
  const float* pb = w2 + ((size_t)e * H_DIM + n0 + r0) * F_DIM + gc * 8;
  const int offB = LOFF(r0, gc * 16);

  const int arow0 = wave * 16 + (lane >> 3);
  const int arow1 = arow0 + 8;
  const int gcolb = (((lane & 7) << 4) ^ (((lane >> 3) & 7) << 4));
  const int enA0 = elist[arow0 < rem ? arow0 : 0];
  const int enA1 = elist[arow1 < rem ? arow1 : 0];
  const unsigned short* ga0 = hb + (size_t)enA0 * F_DIM + (gcolb >> 1);
  const unsigned short* ga1 = hb + (size_t)enA1 * F_DIM + (gcolb >> 1);
  const int aw = wave * 1024;

  const int rowA0 = wm * 32 + (lane & 15);
  const int rowA1 = rowA0 + 16;
  const int rowB0 = wn * 32 + (lane & 15);
  const int rowB1 = rowB0 + 16;
  const int kb = (lane >> 4) * 16;

  const f32x4 zero = {0.f, 0.f, 0.f, 0.f};
  f32x4 ac[2][2];
#pragma unroll
  for (int i = 0; i < 2; i++)
#pragma unroll
    for (int j = 0; j < 2; j++) ac[i][j] = zero;

  dma16(ga0, sA[0] + aw);
  dma16(ga1, sA[0] + aw + 512);
  float4 P[2], Q[2];
  P[0] = *(const float4*)(pb);      P[1] = *(const float4*)(pb + 4);
  Q[0] = *(const float4*)(pb + BK); Q[1] = *(const float4*)(pb + BK + 4);

  const int NT = F_DIM / BK;  // 22 (even)
  for (int t = 0; t < NT; t += 2) {
    const int ka1 = (t + 1 < NT) ? (t + 1) * BK : 0;
    const int ka2 = (t + 2 < NT) ? (t + 2) * BK : 0;
    const int kb2 = ka2;
    const int kb3 = (t + 3 < NT) ? (t + 3) * BK : 0;
    G2_STEP(sA[0], sA[1], P, ka1, kb2);
    G2_STEP(sA[1], sA[0], Q, ka2, kb3);
  }

#pragma unroll
  for (int i = 0; i < 2; i++) {
#pragma unroll
    for (int r = 0; r < 4; r++) {
      const int m = wm * 32 + i * 16 + ((lane >> 4) << 2) + r;
      if (m < rem) {
        const int entry = elist[m];
        const int tok = entry >> 1;
        const float wgt = wl[m];
        float* op = out + (size_t)tok * H_DIM + n0 + wn * 32 + (lane & 15);
#pragma unroll
        for (int j = 0; j < 2; j++) atomicAdd(op + j * 16, wgt * ac[i][j][r]);
      }
    }
  }
}

extern "C" void kernel_launch(void* const* d_in, const int* in_sizes, int n_in,
                              void* d_out, int out_size, void* d_ws, size_t ws_size,
                              hipStream_t stream) {
  const float* x  = (const float*)d_in[0];
  const float* gw = (const float*)d_in[1];
  const float* w1 = (const float*)d_in[2];
  const float* w3 = (const float*)d_in[3];
  const float* w2 = (const float*)d_in[4];
  float* out = (float*)d_out;
  float* logits = out + (size_t)T_TOK * H_DIM;

  char* ws = (char*)d_ws;
  size_t off = 0;
  unsigned short* xb = (unsigned short*)(ws + off); off += (size_t)T_TOK * H_DIM * 2;      // 8 MB
  unsigned short* hb = (unsigned short*)(ws + off); off += (size_t)T_TOK * 2 * F_DIM * 2;  // 11.5 MB
  int*   tk_idx = (int*)(ws + off);   off += (size_t)T_TOK * 2 * 4;
  float* tk_w   = (float*)(ws + off); off += (size_t)T_TOK * 2 * 4;
  int*   counts = (int*)(ws + off);   off += 256;
  int*   entries = (int*)(ws + off);  off += (size_t)N_EXP * T_TOK * 4;
  float* wlist  = (float*)(ws + off); off += (size_t)N_EXP * T_TOK * 4;
  int*   items  = (int*)(ws + off);   off += 256;

  (void)hipMemsetAsync(d_out, 0, (size_t)out_size * sizeof(float), stream);
  router_kernel<<<dim3(T_TOK), 512, 0, stream>>>(x, gw, logits, tk_idx, tk_w, xb);
  build_lists<<<dim3(N_EXP), 64, 0, stream>>>(tk_idx, tk_w, counts, entries, wlist);
  build_items<<<dim3(1), 64, 0, stream>>>(counts, items);
  moe_gemm1<<<dim3(NITEM * G1_NY), 512, 0, stream>>>(w1, w3, xb, counts, entries, items, hb);
  moe_gemm2<<<dim3(NITEM * G2_NY), 512, 0, stream>>>(w2, hb, counts, entries, wlist, items, out);
}